// Round 5
// baseline (50.067 us; speedup 1.0000x reference)
//
#include <hip/hip_runtime.h>

// ---------------------------------------------------------------------------
// StructuralConstraints: RNA base-pair mask + stacking-energy update.
// ref: mask[b,i,j] = valid(si,sj) * (|i-j|>=3 & i<len & j<len)
//      updated[b,i,j] = bp[b,i,j] + add[b,i,j] + add[b,j,i]
//      add[b,i,j] = S(i,j) + (i>=1 && j<=L-2 ? S(i-1,j+1) : 0)
//      S(r,c) = region(r,c) ? E[seq[r],seq[c],seq[(r+1)%L],seq[(c-1)%L]] : 0
// Memory-bound: 64 MiB read + 128 MiB write compulsory per call.
// R2: no-LDS/no-barrier; E sub-tables as 64-bit nibble constants in SGPRs.
// R3: nontemporal stores (34.5us, 5.83 TB/s).
// R4: burst coarsening — 128 thr/block, 8 floats/thread: each wave reads
//     2 KiB contiguous (2x f4) and stores 2 KiB bursts per output stream,
//     halving wave count and coarsening R/W interleave at the controllers.
// ---------------------------------------------------------------------------

typedef float f4 __attribute__((ext_vector_type(4)));
typedef int   i4 __attribute__((ext_vector_type(4)));

constexpr bool vp(int a, int b) { return (a - b == 1) || (b - a == 1); }

// E * 10 as an integer (values {0,5,7,8,9,10,11,13} all fit in a nibble)
constexpr int ei(int a, int b, int c, int d) {
    if (!vp(a, b) || !vp(c, d)) return 0;
    if (a == 0 && b == 1) {               // (A,U) outer
        if (c == 0 && d == 1) return 9;   // 0.9
        if (c == 2 && d == 3) return 11;  // 1.1
        if (c == 2 && d == 1) return 8;   // 0.8
    }
    if (a == 2 && b == 3) {               // (G,C) outer
        if (c == 0 && d == 1) return 11;  // 1.1
        if (c == 2 && d == 3) return 13;  // 1.3
        if (c == 2 && d == 1) return 10;  // 1.0
    }
    if (a == 2 && b == 1) {               // (G,U) outer
        if (c == 0 && d == 1) return 8;   // 0.8
        if (c == 2 && d == 3) return 10;  // 1.0
        if (c == 2 && d == 1) return 7;   // 0.7
    }
    return 5;                             // default 0.5
}

struct ETabs {
    unsigned long long fwd[16];  // fwd[a*4+c]: nibble (b*4+d) = ei(a,b,c,d)
    unsigned long long tr[16];   // tr [b*4+d]: nibble (a*4+c) = ei(a,b,c,d)
};

constexpr ETabs make_tabs() {
    ETabs t{};
    for (int a = 0; a < 4; ++a)
    for (int c = 0; c < 4; ++c) {
        unsigned long long v = 0;
        for (int b = 0; b < 4; ++b)
        for (int d = 0; d < 4; ++d)
            v |= (unsigned long long)ei(a, b, c, d) << ((b * 4 + d) * 4);
        t.fwd[a * 4 + c] = v;
    }
    for (int b = 0; b < 4; ++b)
    for (int d = 0; d < 4; ++d) {
        unsigned long long v = 0;
        for (int a = 0; a < 4; ++a)
        for (int c = 0; c < 4; ++c)
            v |= (unsigned long long)ei(a, b, c, d) << ((a * 4 + c) * 4);
        t.tr[b * 4 + d] = v;
    }
    return t;
}

__device__ __constant__ ETabs cT = make_tabs();

__device__ __forceinline__ float nibf(unsigned long long t, int idx) {
    return (float)((unsigned)(t >> (idx << 2)) & 15u) * 0.1f;
}

// One block per (b, i) row; 128 threads; each thread does 8 consecutive j.
// No LDS, no barriers.
__global__ __launch_bounds__(128) void sc_kernel(
    const float* __restrict__ bp,
    const int*   __restrict__ seq,
    const int*   __restrict__ lens,
    float* __restrict__ mask_out,
    float* __restrict__ upd_out,
    int L)
{
    const int i   = blockIdx.x;
    const int b   = blockIdx.y;
    const int tid = threadIdx.x;
    const int len = lens[b];
    const int* srow = seq + (size_t)b * L;

    // wave-uniform row codes + packed tables (scalar loads, no LDS)
    const int si   = srow[i];
    const int sim1 = srow[(i == 0)     ? (L - 1) : (i - 1)];
    const int sip1 = srow[(i == L - 1) ? 0       : (i + 1)];

    const unsigned long long T1 = cT.fwd[si   * 4 + sip1];  // S(i,j):     idx sj*4+sjm
    const unsigned long long T2 = cT.fwd[sim1 * 4 + si  ];  // S(i-1,j+1): idx sjp*4+sj
    const unsigned long long T3 = cT.tr [si   * 4 + sim1];  // S(j,i):     idx sj*4+sjp
    const unsigned long long T4 = cT.tr [sip1 * 4 + si  ];  // S(j-1,i+1): idx sjm*4+sj

    const size_t rowoff     = ((size_t)b * L + i) * L;
    const bool   i_lt_len   = i < len;
    const bool   i_lt_lenm1 = i < len - 1;
    const bool   ip1_lt_len = (i + 1) < len;
    const bool   i_ge_1     = i >= 1;

    const int j0 = tid << 3;  // 128 threads x 8 floats = 1024 = L, one pass

    // j-neighborhood codes straight from global (L1/L2-hot 4KiB row)
    const i4 s4a = *(const i4*)&srow[j0];
    const i4 s4b = *(const i4*)&srow[j0 + 4];
    const int sm = srow[(j0 == 0)     ? (L - 1) : (j0 - 1)];
    const int sp = srow[(j0 + 8 == L) ? 0       : (j0 + 8)];

    const int sj_[8]  = { s4a[0], s4a[1], s4a[2], s4a[3],
                          s4b[0], s4b[1], s4b[2], s4b[3] };
    const int sjm_[8] = { sm,     s4a[0], s4a[1], s4a[2],
                          s4a[3], s4b[0], s4b[1], s4b[2] };
    const int sjp_[8] = { s4a[1], s4a[2], s4a[3], s4b[0],
                          s4b[1], s4b[2], s4b[3], sp     };

    // 2 KiB contiguous read burst per wave (two back-to-back f4 loads)
    const f4 bpA = *(const f4*)&bp[rowoff + j0];
    const f4 bpB = *(const f4*)&bp[rowoff + j0 + 4];

    f4 mvA, uvA, mvB, uvB;
    #pragma unroll
    for (int k = 0; k < 8; ++k) {
        const int j = j0 + k;
        const int d = j - i;
        const bool j_lt_len = j < len;

        const bool pair_ok = ((si - sj_[k]) == 1) || ((sj_[k] - si) == 1);
        const float m = (pair_ok && (d >= 3 || d <= -3) && i_lt_len && j_lt_len)
                            ? 1.0f : 0.0f;

        float s = (k < 4) ? bpA[k] : bpB[k - 4];
        if (d >= 2) {           // forward: S(i,j) + S(i-1,j+1)
            const float s1 = (d >= 4 && i_lt_lenm1 && j_lt_len)
                               ? nibf(T1, sj_[k] * 4 + sjm_[k]) : 0.0f;
            const float s2 = (i_ge_1 && i_lt_len && (j + 1) < len)
                               ? nibf(T2, sjp_[k] * 4 + sj_[k]) : 0.0f;
            s += s1 + s2;
        } else if (d <= -2) {   // transposed: S(j,i) + S(j-1,i+1)
            const float s3 = (d <= -4 && (j < len - 1) && i_lt_len)
                               ? nibf(T3, sj_[k] * 4 + sjp_[k]) : 0.0f;
            const float s4v = (j >= 1 && j_lt_len && ip1_lt_len)
                               ? nibf(T4, sjm_[k] * 4 + sj_[k]) : 0.0f;
            s += s3 + s4v;
        }
        if (k < 4) { mvA[k] = m; uvA[k] = s; }
        else       { mvB[k - 4] = m; uvB[k - 4] = s; }
    }

    // 2 KiB store bursts per stream: mask pair, then updated pair
    __builtin_nontemporal_store(mvA, (f4*)&mask_out[rowoff + j0]);
    __builtin_nontemporal_store(mvB, (f4*)&mask_out[rowoff + j0 + 4]);
    __builtin_nontemporal_store(uvA, (f4*)&upd_out [rowoff + j0]);
    __builtin_nontemporal_store(uvB, (f4*)&upd_out [rowoff + j0 + 4]);
}

extern "C" void kernel_launch(void* const* d_in, const int* in_sizes, int n_in,
                              void* d_out, int out_size, void* d_ws, size_t ws_size,
                              hipStream_t stream) {
    const float* bp   = (const float*)d_in[0];
    const int*   seq  = (const int*)d_in[1];
    const int*   lens = (const int*)d_in[2];

    const int B = in_sizes[2];
    const int L = in_sizes[1] / B;

    float* mask_out = (float*)d_out;
    float* upd_out  = (float*)d_out + (size_t)B * L * L;

    dim3 grid(L, B);
    sc_kernel<<<grid, 128, 0, stream>>>(bp, seq, lens, mask_out, upd_out, L);
}

// Round 6
// 40.593 us; speedup vs baseline: 1.2334x; 1.2334x over previous
//
#include <hip/hip_runtime.h>

// ---------------------------------------------------------------------------
// StructuralConstraints: RNA base-pair mask + stacking-energy update.
// ref: mask[b,i,j] = valid(si,sj) * (|i-j|>=3 & i<len & j<len)
//      updated[b,i,j] = bp[b,i,j] + add[b,i,j] + add[b,j,i]
//      add[b,i,j] = S(i,j) + (i>=1 && j<=L-2 ? S(i-1,j+1) : 0)
//      S(r,c) = region(r,c) ? E[seq[r],seq[c],seq[(r+1)%L],seq[(c-1)%L]] : 0
// Memory-bound: 64 MiB read + 128 MiB write compulsory -> ~31us floor.
// R2: no-LDS/no-barrier; E sub-tables as 64-bit nibble constants in SGPRs.
// R3: nontemporal stores (34.5us, 5.83 TB/s). R4: stride-32B/lane = wrong.
// R5: persistent grid-stride (2048 blocks x 256 thr, 8 rows/block) with
//     1-deep prefetch of next row's f4 -> 2 loads in flight per thread,
//     lane-contiguous 16 B/lane preserved, wave-uniform scalar tables.
// ---------------------------------------------------------------------------

typedef float f4 __attribute__((ext_vector_type(4)));
typedef int   i4 __attribute__((ext_vector_type(4)));

constexpr bool vp(int a, int b) { return (a - b == 1) || (b - a == 1); }

// E * 10 as an integer (values {0,5,7,8,9,10,11,13} all fit in a nibble)
constexpr int ei(int a, int b, int c, int d) {
    if (!vp(a, b) || !vp(c, d)) return 0;
    if (a == 0 && b == 1) {               // (A,U) outer
        if (c == 0 && d == 1) return 9;   // 0.9
        if (c == 2 && d == 3) return 11;  // 1.1
        if (c == 2 && d == 1) return 8;   // 0.8
    }
    if (a == 2 && b == 3) {               // (G,C) outer
        if (c == 0 && d == 1) return 11;  // 1.1
        if (c == 2 && d == 3) return 13;  // 1.3
        if (c == 2 && d == 1) return 10;  // 1.0
    }
    if (a == 2 && b == 1) {               // (G,U) outer
        if (c == 0 && d == 1) return 8;   // 0.8
        if (c == 2 && d == 3) return 10;  // 1.0
        if (c == 2 && d == 1) return 7;   // 0.7
    }
    return 5;                             // default 0.5
}

struct ETabs {
    unsigned long long fwd[16];  // fwd[a*4+c]: nibble (b*4+d) = ei(a,b,c,d)
    unsigned long long tr[16];   // tr [b*4+d]: nibble (a*4+c) = ei(a,b,c,d)
};

constexpr ETabs make_tabs() {
    ETabs t{};
    for (int a = 0; a < 4; ++a)
    for (int c = 0; c < 4; ++c) {
        unsigned long long v = 0;
        for (int b = 0; b < 4; ++b)
        for (int d = 0; d < 4; ++d)
            v |= (unsigned long long)ei(a, b, c, d) << ((b * 4 + d) * 4);
        t.fwd[a * 4 + c] = v;
    }
    for (int b = 0; b < 4; ++b)
    for (int d = 0; d < 4; ++d) {
        unsigned long long v = 0;
        for (int a = 0; a < 4; ++a)
        for (int c = 0; c < 4; ++c)
            v |= (unsigned long long)ei(a, b, c, d) << ((a * 4 + c) * 4);
        t.tr[b * 4 + d] = v;
    }
    return t;
}

__device__ __constant__ ETabs cT = make_tabs();

__device__ __forceinline__ float nibf(unsigned long long t, int idx) {
    return (float)((unsigned)(t >> (idx << 2)) & 15u) * 0.1f;
}

// Persistent: each block walks rows R = bid, bid+gridDim.x, ...
// 256 threads, thread j0 = tid*4 (16 B/lane, lane-contiguous).
__global__ __launch_bounds__(256) void sc_kernel(
    const float* __restrict__ bp,
    const int*   __restrict__ seq,
    const int*   __restrict__ lens,
    float* __restrict__ mask_out,
    float* __restrict__ upd_out,
    int L, int nRows)
{
    const int tid = threadIdx.x;
    const int j0  = tid << 2;
    const int stride = gridDim.x;

    int R = blockIdx.x;
    // prefetch first row's quad
    f4 bp4 = *(const f4*)&bp[(size_t)R * L + j0];

    while (R < nRows) {
        const int Rn = R + stride;
        f4 bp4n;
        if (Rn < nRows)
            bp4n = *(const f4*)&bp[(size_t)Rn * L + j0];  // in flight during compute

        const int b = R / L;
        const int i = R - b * L;
        const int len = lens[b];
        const int* srow = seq + (size_t)b * L;

        // wave-uniform row codes + packed tables (scalar loads)
        const int si   = srow[i];
        const int sim1 = srow[(i == 0)     ? (L - 1) : (i - 1)];
        const int sip1 = srow[(i == L - 1) ? 0       : (i + 1)];

        const unsigned long long T1 = cT.fwd[si   * 4 + sip1];  // S(i,j)
        const unsigned long long T2 = cT.fwd[sim1 * 4 + si  ];  // S(i-1,j+1)
        const unsigned long long T3 = cT.tr [si   * 4 + sim1];  // S(j,i)
        const unsigned long long T4 = cT.tr [sip1 * 4 + si  ];  // S(j-1,i+1)

        const size_t rowoff     = (size_t)R * L;
        const bool   i_lt_len   = i < len;
        const bool   i_lt_lenm1 = i < len - 1;
        const bool   ip1_lt_len = (i + 1) < len;
        const bool   i_ge_1     = i >= 1;

        // j-neighborhood codes (L1/L2-hot 4KiB row)
        const i4 s4 = *(const i4*)&srow[j0];
        const int sm = srow[(j0 == 0)     ? (L - 1) : (j0 - 1)];
        const int sp = srow[(j0 + 4 == L) ? 0       : (j0 + 4)];
        const int sj_[4]  = { s4[0], s4[1], s4[2], s4[3] };
        const int sjm_[4] = { sm,    s4[0], s4[1], s4[2] };
        const int sjp_[4] = { s4[1], s4[2], s4[3], sp    };

        f4 mv, uv;
        #pragma unroll
        for (int k = 0; k < 4; ++k) {
            const int j = j0 + k;
            const int d = j - i;
            const bool j_lt_len = j < len;

            const bool pair_ok = ((si - sj_[k]) == 1) || ((sj_[k] - si) == 1);
            mv[k] = (pair_ok && (d >= 3 || d <= -3) && i_lt_len && j_lt_len)
                        ? 1.0f : 0.0f;

            float s = bp4[k];
            if (d >= 2) {           // forward: S(i,j) + S(i-1,j+1)
                const float s1 = (d >= 4 && i_lt_lenm1 && j_lt_len)
                                   ? nibf(T1, sj_[k] * 4 + sjm_[k]) : 0.0f;
                const float s2 = (i_ge_1 && i_lt_len && (j + 1) < len)
                                   ? nibf(T2, sjp_[k] * 4 + sj_[k]) : 0.0f;
                s += s1 + s2;
            } else if (d <= -2) {   // transposed: S(j,i) + S(j-1,i+1)
                const float s3 = (d <= -4 && (j < len - 1) && i_lt_len)
                                   ? nibf(T3, sj_[k] * 4 + sjp_[k]) : 0.0f;
                const float s4v = (j >= 1 && j_lt_len && ip1_lt_len)
                                   ? nibf(T4, sjm_[k] * 4 + sj_[k]) : 0.0f;
                s += s3 + s4v;
            }
            uv[k] = s;
        }

        __builtin_nontemporal_store(mv, (f4*)&mask_out[rowoff + j0]);
        __builtin_nontemporal_store(uv, (f4*)&upd_out [rowoff + j0]);

        R = Rn;
        bp4 = bp4n;
    }
}

extern "C" void kernel_launch(void* const* d_in, const int* in_sizes, int n_in,
                              void* d_out, int out_size, void* d_ws, size_t ws_size,
                              hipStream_t stream) {
    const float* bp   = (const float*)d_in[0];
    const int*   seq  = (const int*)d_in[1];
    const int*   lens = (const int*)d_in[2];

    const int B = in_sizes[2];
    const int L = in_sizes[1] / B;
    const int nRows = B * L;

    float* mask_out = (float*)d_out;
    float* upd_out  = (float*)d_out + (size_t)B * L * L;

    const int nBlocks = 2048;  // 8 blocks/CU, 8 rows per block
    sc_kernel<<<nBlocks, 256, 0, stream>>>(bp, seq, lens, mask_out, upd_out,
                                           L, nRows);
}

// Round 7
// 34.402 us; speedup vs baseline: 1.4554x; 1.1800x over previous
//
#include <hip/hip_runtime.h>

// ---------------------------------------------------------------------------
// StructuralConstraints: RNA base-pair mask + stacking-energy update.
// ref: mask[b,i,j] = valid(si,sj) * (|i-j|>=3 & i<len & j<len)
//      updated[b,i,j] = bp[b,i,j] + add[b,i,j] + add[b,j,i]
//      add[b,i,j] = S(i,j) + (i>=1 && j<=L-2 ? S(i-1,j+1) : 0)
//      S(r,c) = region(r,c) ? E[seq[r],seq[c],seq[(r+1)%L],seq[(c-1)%L]] : 0
// Memory-bound: 64 MiB read + 128 MiB write compulsory -> ~31us floor.
// FINAL = R3 (best measured: 34.5us, 5.83 TB/s effective):
//   - one (b,i) row per 256-thread block, 4 floats/thread, 16 B/lane
//   - no LDS, no barriers; E sub-tables as 64-bit nibble constants read
//     via 4 uniform scalar loads (lookup = shift/mask * 0.1f)
//   - nontemporal stores (outputs never re-read)
// Structural variants measured and REJECTED: ROWS=4/block (41.5us),
// 8 floats/thread burst (50.1us, breaks 16B/lane coalescing),
// persistent grid + 1-deep prefetch (40.6us, kills page locality).
// ---------------------------------------------------------------------------

typedef float f4 __attribute__((ext_vector_type(4)));
typedef int   i4 __attribute__((ext_vector_type(4)));

constexpr bool vp(int a, int b) { return (a - b == 1) || (b - a == 1); }

// E * 10 as an integer (values {0,5,7,8,9,10,11,13} all fit in a nibble)
constexpr int ei(int a, int b, int c, int d) {
    if (!vp(a, b) || !vp(c, d)) return 0;
    if (a == 0 && b == 1) {               // (A,U) outer
        if (c == 0 && d == 1) return 9;   // 0.9
        if (c == 2 && d == 3) return 11;  // 1.1
        if (c == 2 && d == 1) return 8;   // 0.8
    }
    if (a == 2 && b == 3) {               // (G,C) outer
        if (c == 0 && d == 1) return 11;  // 1.1
        if (c == 2 && d == 3) return 13;  // 1.3
        if (c == 2 && d == 1) return 10;  // 1.0
    }
    if (a == 2 && b == 1) {               // (G,U) outer
        if (c == 0 && d == 1) return 8;   // 0.8
        if (c == 2 && d == 3) return 10;  // 1.0
        if (c == 2 && d == 1) return 7;   // 0.7
    }
    return 5;                             // default 0.5
}

struct ETabs {
    unsigned long long fwd[16];  // fwd[a*4+c]: nibble (b*4+d) = ei(a,b,c,d)
    unsigned long long tr[16];   // tr [b*4+d]: nibble (a*4+c) = ei(a,b,c,d)
};

constexpr ETabs make_tabs() {
    ETabs t{};
    for (int a = 0; a < 4; ++a)
    for (int c = 0; c < 4; ++c) {
        unsigned long long v = 0;
        for (int b = 0; b < 4; ++b)
        for (int d = 0; d < 4; ++d)
            v |= (unsigned long long)ei(a, b, c, d) << ((b * 4 + d) * 4);
        t.fwd[a * 4 + c] = v;
    }
    for (int b = 0; b < 4; ++b)
    for (int d = 0; d < 4; ++d) {
        unsigned long long v = 0;
        for (int a = 0; a < 4; ++a)
        for (int c = 0; c < 4; ++c)
            v |= (unsigned long long)ei(a, b, c, d) << ((a * 4 + c) * 4);
        t.tr[b * 4 + d] = v;
    }
    return t;
}

__device__ __constant__ ETabs cT = make_tabs();

__device__ __forceinline__ float nibf(unsigned long long t, int idx) {
    return (float)((unsigned)(t >> (idx << 2)) & 15u) * 0.1f;
}

// One block per (b, i) row; 256 threads; each thread does 4 consecutive j.
// No LDS, no barriers.
__global__ __launch_bounds__(256) void sc_kernel(
    const float* __restrict__ bp,
    const int*   __restrict__ seq,
    const int*   __restrict__ lens,
    float* __restrict__ mask_out,
    float* __restrict__ upd_out,
    int L)
{
    const int i   = blockIdx.x;
    const int b   = blockIdx.y;
    const int tid = threadIdx.x;
    const int len = lens[b];
    const int* srow = seq + (size_t)b * L;

    // wave-uniform row codes + packed tables (scalar loads, no LDS)
    const int si   = srow[i];
    const int sim1 = srow[(i == 0)     ? (L - 1) : (i - 1)];
    const int sip1 = srow[(i == L - 1) ? 0       : (i + 1)];

    const unsigned long long T1 = cT.fwd[si   * 4 + sip1];  // S(i,j):     idx sj*4+sjm
    const unsigned long long T2 = cT.fwd[sim1 * 4 + si  ];  // S(i-1,j+1): idx sjp*4+sj
    const unsigned long long T3 = cT.tr [si   * 4 + sim1];  // S(j,i):     idx sj*4+sjp
    const unsigned long long T4 = cT.tr [sip1 * 4 + si  ];  // S(j-1,i+1): idx sjm*4+sj

    const size_t rowoff     = ((size_t)b * L + i) * L;
    const bool   i_lt_len   = i < len;
    const bool   i_lt_lenm1 = i < len - 1;
    const bool   ip1_lt_len = (i + 1) < len;
    const bool   i_ge_1     = i >= 1;

    for (int j0 = tid << 2; j0 < L; j0 += (int)blockDim.x << 2) {
        // j-neighborhood codes straight from global (L1/L2-hot 4KiB row)
        const i4 s4 = *(const i4*)&srow[j0];
        const int sm = srow[(j0 == 0)     ? (L - 1) : (j0 - 1)];
        const int sp = srow[(j0 + 4 == L) ? 0       : (j0 + 4)];
        const int sj_[4]  = { s4[0], s4[1], s4[2], s4[3] };
        const int sjm_[4] = { sm,    s4[0], s4[1], s4[2] };
        const int sjp_[4] = { s4[1], s4[2], s4[3], sp    };

        const f4 bp4 = *(const f4*)&bp[rowoff + j0];

        f4 mv, uv;
        #pragma unroll
        for (int k = 0; k < 4; ++k) {
            const int j = j0 + k;
            const int d = j - i;
            const bool j_lt_len = j < len;

            const bool pair_ok = ((si - sj_[k]) == 1) || ((sj_[k] - si) == 1);
            mv[k] = (pair_ok && (d >= 3 || d <= -3) && i_lt_len && j_lt_len)
                        ? 1.0f : 0.0f;

            float s = bp4[k];
            if (d >= 2) {           // forward: S(i,j) + S(i-1,j+1)
                const float s1 = (d >= 4 && i_lt_lenm1 && j_lt_len)
                                   ? nibf(T1, sj_[k] * 4 + sjm_[k]) : 0.0f;
                const float s2 = (i_ge_1 && i_lt_len && (j + 1) < len)
                                   ? nibf(T2, sjp_[k] * 4 + sj_[k]) : 0.0f;
                s += s1 + s2;
            } else if (d <= -2) {   // transposed: S(j,i) + S(j-1,i+1)
                const float s3 = (d <= -4 && (j < len - 1) && i_lt_len)
                                   ? nibf(T3, sj_[k] * 4 + sjp_[k]) : 0.0f;
                const float s4v = (j >= 1 && j_lt_len && ip1_lt_len)
                                   ? nibf(T4, sjm_[k] * 4 + sj_[k]) : 0.0f;
                s += s3 + s4v;
            }
            uv[k] = s;
        }

        __builtin_nontemporal_store(mv, (f4*)&mask_out[rowoff + j0]);
        __builtin_nontemporal_store(uv, (f4*)&upd_out [rowoff + j0]);
    }
}

extern "C" void kernel_launch(void* const* d_in, const int* in_sizes, int n_in,
                              void* d_out, int out_size, void* d_ws, size_t ws_size,
                              hipStream_t stream) {
    const float* bp   = (const float*)d_in[0];
    const int*   seq  = (const int*)d_in[1];
    const int*   lens = (const int*)d_in[2];

    const int B = in_sizes[2];
    const int L = in_sizes[1] / B;

    float* mask_out = (float*)d_out;
    float* upd_out  = (float*)d_out + (size_t)B * L * L;

    dim3 grid(L, B);
    sc_kernel<<<grid, 256, 0, stream>>>(bp, seq, lens, mask_out, upd_out, L);
}